// Round 5
// baseline (82.797 us; speedup 1.0000x reference)
//
#include <hip/hip_runtime.h>
#include <hip/hip_bf16.h>

// Problem constants (fixed by reference)
#define NB    2
#define HW    25600      // 160*160
#define WDIM  160
#define NSTG  9

// ---- DPP add (full-rate VALU, no LDS pipe) ----
template <int CTRL>
__device__ __forceinline__ float dpp_add(float v) {
    int moved = __builtin_amdgcn_update_dpp(0, __float_as_int(v), CTRL, 0xf, 0xf, true);
    return v + __int_as_float(moved);
}

// sum over each 8-lane group, broadcast to all 8 lanes — pure DPP, no LDS.
__device__ __forceinline__ float reduce8(float v) {
    v = dpp_add<0xB1>(v);    // quad_perm [1,0,3,2] : xor 1
    v = dpp_add<0x4E>(v);    // quad_perm [2,3,0,1] : xor 2
    v = dpp_add<0x141>(v);   // row_half_mirror     : cross-quad within 8
    return v;
}

// One fused kernel: head 1x1 conv (recomputed per gather position),
// rank-collapsed 9-stage iteration, tail 1x1 conv.
// Layout: 8 lanes per pixel, 4 channels per lane, TWO pixels per lane (ILP)
// -> 16 pixels/wave, 3200 waves, ~6 independent chains per SIMD.
__global__ __launch_bounds__(256, 3) void fused_kernel(const float* __restrict__ x,
                                                       const float* __restrict__ head_w,
                                                       const float* __restrict__ tail_w,
                                                       const float* __restrict__ alphas,
                                                       const float* __restrict__ betas,
                                                       float* __restrict__ out) {
    int sub = threadIdx.x & 7;              // channel group: channels 4*sub .. 4*sub+3
    int g   = (threadIdx.x >> 3) & 7;       // 8-lane group index within wave
    int wib = threadIdx.x >> 6;             // wave within block
    int b   = blockIdx.x / 400;             // 64 px/block -> 400 blocks per image
    int base = blockIdx.x * 64 + wib * 16 - b * HW;   // s-coordinate base
    int s2[2] = { base + g, base + 8 + g };

    // head weights for my 4 channels: head_w is [32][3]
    int c0 = sub * 4;
    float hwv[4][3];
#pragma unroll
    for (int j = 0; j < 4; ++j)
#pragma unroll
        for (int ci = 0; ci < 3; ++ci)
            hwv[j][ci] = head_w[(c0 + j) * 3 + ci];

    const float* xb0 = x + b * 3 * HW;
    const float* xb1 = xb0 + HW;
    const float* xb2 = xb1 + HW;

    // Gather X through the torch-unfold+reshape scramble (channel-preserving),
    // head conv on the fly. Two independent pixels -> two load/FMA streams.
    float X[2][9][4];
#pragma unroll
    for (int px = 0; px < 2; ++px) {
        int ss  = s2[px];
        int g9  = ss * 9;
        int kk0 = g9 / HW;
        int r0  = g9 - kk0 * HW;
        int h0  = r0 / WDIM;
        int w0  = r0 - h0 * WDIM;
        int ki0 = kk0 / 3;
        int dh0 = ki0 - 1, dw0 = kk0 - ki0 * 3 - 1;
        int kk1 = kk0 + 1;
        int ki1 = kk1 / 3;
        int dh1 = ki1 - 1, dw1 = kk1 - ki1 * 3 - 1;
#pragma unroll
        for (int k2 = 0; k2 < 9; ++k2) {
            int r  = r0 + k2;
            int wn = w0 + k2;
            int cw = (wn >= WDIM);
            int w1 = cw ? wn - WDIM : wn;
            int h1 = h0 + cw;
            bool wr = (r >= HW);
            int h  = wr ? 0 : h1;
            int w  = wr ? r - HW : w1;
            int dh = wr ? dh1 : dh0;
            int dw = wr ? dw1 : dw0;
            int hh = min(max(h + dh, 0), 159);
            int ww = min(max(w + dw, 0), 159);
            int p  = hh * WDIM + ww;
            float x0 = xb0[p], x1 = xb1[p], x2 = xb2[p];
#pragma unroll
            for (int j = 0; j < 4; ++j)
                X[px][k2][j] = fmaxf(hwv[j][0] * x0 + hwv[j][1] * x1 + hwv[j][2] * x2, 0.f);
        }
    }

    // init: u[c] = mean_k X ; v[k] = mean_c X
    float u[2][4];
#pragma unroll
    for (int px = 0; px < 2; ++px)
#pragma unroll
        for (int j = 0; j < 4; ++j) {
            float a = X[px][0][j];
#pragma unroll
            for (int k = 1; k < 9; ++k) a += X[px][k][j];
            u[px][j] = a * (1.f / 9.f);
        }
    float v[2][9];
#pragma unroll
    for (int k = 0; k < 9; ++k)
#pragma unroll
        for (int px = 0; px < 2; ++px) {
            float pr = (X[px][k][0] + X[px][k][1]) + (X[px][k][2] + X[px][k][3]);
            v[px][k] = reduce8(pr) * (1.f / 32.f);
        }

    // 9 stages (rank-collapsed: all 3 ranks provably identical)
#pragma unroll
    for (int i = 0; i < NSTG; ++i) {
        float beta  = betas[i];
        float alpha = alphas[i];
        float vs[2];
#pragma unroll
        for (int px = 0; px < 2; ++px) {
            float sp = (u[px][0] * u[px][0] + u[px][1] * u[px][1])
                     + (u[px][2] * u[px][2] + u[px][3] * u[px][3]);
            vs[px] = 1.f - 3.f * beta * reduce8(sp);
        }
#pragma unroll
        for (int k = 0; k < 9; ++k)
#pragma unroll
            for (int px = 0; px < 2; ++px) {
                float qp = (u[px][0] * X[px][k][0] + u[px][1] * X[px][k][1])
                         + (u[px][2] * X[px][k][2] + u[px][3] * X[px][k][3]);
                float q  = reduce8(qp);
                v[px][k] = v[px][k] * vs[px] + beta * q;
            }
#pragma unroll
        for (int px = 0; px < 2; ++px) {
            float t = ((v[px][0] * v[px][0] + v[px][1] * v[px][1])
                     + (v[px][2] * v[px][2] + v[px][3] * v[px][3]))
                    + ((v[px][4] * v[px][4] + v[px][5] * v[px][5])
                     + (v[px][6] * v[px][6] + v[px][7] * v[px][7]))
                    +  v[px][8] * v[px][8];
            float us = 1.f - 3.f * alpha * t;
#pragma unroll
            for (int j = 0; j < 4; ++j) {
                float m = X[px][0][j] * v[px][0];
#pragma unroll
                for (int k = 1; k < 9; ++k) m += X[px][k][j] * v[px][k];
                u[px][j] = u[px][j] * us + alpha * m;
            }
        }
    }

    // epilogue: UVc[c] = 3*u[c]*v[center=4]; out[o] = relu(sum_c UVc * tail_w[o*32+c])
#pragma unroll
    for (int px = 0; px < 2; ++px) {
        float v4 = v[px][4];
        float uvc[4];
#pragma unroll
        for (int j = 0; j < 4; ++j) uvc[j] = 3.f * u[px][j] * v4;
        float o[3];
#pragma unroll
        for (int oo = 0; oo < 3; ++oo) {
            const float* tw = tail_w + oo * 32 + c0;
            float pr = (uvc[0] * tw[0] + uvc[1] * tw[1]) + (uvc[2] * tw[2] + uvc[3] * tw[3]);
            o[oo] = fmaxf(reduce8(pr), 0.f);
        }
        if (sub == 0) {
            float* op = out + b * 3 * HW + s2[px];
            op[0]      = o[0];
            op[HW]     = o[1];
            op[2 * HW] = o[2];
        }
    }
}

extern "C" void kernel_launch(void* const* d_in, const int* in_sizes, int n_in,
                              void* d_out, int out_size, void* d_ws, size_t ws_size,
                              hipStream_t stream) {
    const float* x      = (const float*)d_in[0];
    const float* head_w = (const float*)d_in[1];
    const float* tail_w = (const float*)d_in[2];
    const float* alphas = (const float*)d_in[3];
    const float* betas  = (const float*)d_in[4];
    float*       out    = (float*)d_out;

    // NB*HW pixels, 16 px/wave, 64 px/block -> 800 blocks of 256
    fused_kernel<<<dim3(NB * HW / 64), dim3(256), 0, stream>>>(
        x, head_w, tail_w, alphas, betas, out);
}